// Round 11
// baseline (604.279 us; speedup 1.0000x reference)
//
#include <hip/hip_runtime.h>

// Problem constants
#define V_  32000
#define E_  256
#define H_  256
#define S_  128
#define B_  64
#define HID_ 30

typedef float f32x2 __attribute__((ext_vector_type(2)));

// HW_REG_XCC_ID (id=20, offset=0, size=4) -> physical XCD of this WG [m09]
#define HWREG_XCC_ID ((3 << 11) | 20)

// Accurate f32 activations (LSTM path)
__device__ __forceinline__ float sigmoid_acc(float x) {
    return 1.0f / (1.0f + expf(-x));
}
__device__ __forceinline__ float tanh_acc(float x) {
    return tanhf(x);
}
// Fast tanh for the scores kernel only (~3e-7 abs err)
__device__ __forceinline__ float fast_tanh(float x) {
    return 1.f - 2.f * __builtin_amdgcn_rcpf(1.f + __expf(2.f * x));
}

// Fast-path exchange ops. gfx950 syntax: offset: must precede cache flags.
// Producer: plain dwordx2 stores (L1 write-through -> XCD L2).
// Consumer: sc0 loads (L1 bypass -> reads shared XCD L2).
__device__ __forceinline__ void store_l2x2(unsigned long long* p,
                                           unsigned long long a,
                                           unsigned long long b) {
    asm volatile("global_store_dwordx2 %2, %0, off\n\t"
                 "global_store_dwordx2 %2, %1, off offset:8"
                 :: "v"(a), "v"(b), "v"(p) : "memory");
}
__device__ __forceinline__ void load_l2x2(const unsigned long long* p,
                                          unsigned long long& a,
                                          unsigned long long& b) {
    asm volatile("global_load_dwordx2 %0, %2, off sc0\n\t"
                 "global_load_dwordx2 %1, %2, off offset:8 sc0\n\t"
                 "s_waitcnt vmcnt(0)"
                 : "=&v"(a), "=&v"(b) : "v"(p) : "memory");
}

// ---------------------------------------------------------------------------
// K0: build sT: per (dir, side) the last 12 cols of each Whh row, transposed
// for coalesced per-step streaming. sT[q][r], q = dir*6+side*3+j.
// ---------------------------------------------------------------------------
__global__ __launch_bounds__(256) void prep_stream_kernel(
    const float* __restrict__ Whh_f, const float* __restrict__ Whh_b,
    float4* __restrict__ sT) {
    int i = blockIdx.x * 256 + threadIdx.x;      // < 12*1024
    if (i >= 12 * 1024) return;
    int r = i & 1023;
    int q = i >> 10;                             // 0..11
    int j = q % 3;
    int side = (q % 6) / 3;
    int dir = q / 6;
    const float* Whh = dir ? Whh_b : Whh_f;
    const float* src = Whh + (size_t)r * H_ + side * 128 + 116 + 4 * j;
    sT[(size_t)q * 1024 + r] = make_float4(src[0], src[1], src[2], src[3]);
}

// ---------------------------------------------------------------------------
// K1: f32 input-projection GEMM with fused embedding gather.
// 128x128 tile, 8x8 per thread, KC=32 via LDS. grid (512, 2), block 256.
// ---------------------------------------------------------------------------
#define GKC 32
#define GLD 132

__global__ __launch_bounds__(256, 4) void gemm2_kernel(
    const int* __restrict__ concepts, const float* __restrict__ embedding,
    const float* __restrict__ Wih_f, const float* __restrict__ Wih_b,
    float* __restrict__ Xg) {
    __shared__ float As[GKC][GLD];
    __shared__ float Bs[GKC][GLD];
    const int dir = blockIdx.y;
    const float* Wih = dir ? Wih_b : Wih_f;
    const int mt = blockIdx.x >> 3;
    const int nt = blockIdx.x & 7;
    const int m0 = mt * 128, n0 = nt * 128;
    const int t = threadIdx.x;
    const int tm = (t & 15) * 4;
    const int tn = (t >> 4) * 4;

    int cid[4], rr[4];
#pragma unroll
    for (int i = 0; i < 4; ++i) {
        int flat = t + 256 * i;
        rr[i] = flat >> 3;
        cid[i] = concepts[m0 + rr[i]];
    }

    float acc[8][8];
#pragma unroll
    for (int i = 0; i < 8; ++i)
#pragma unroll
        for (int j = 0; j < 8; ++j) acc[i][j] = 0.f;

    for (int kk = 0; kk < E_; kk += GKC) {
        __syncthreads();
#pragma unroll
        for (int i = 0; i < 4; ++i) {
            int flat = t + 256 * i;
            int r = rr[i];
            int kq = (flat & 7) * 4;
            float4 av = *(const float4*)&embedding[(size_t)cid[i] * E_ + kk + kq];
            float4 bv = *(const float4*)&Wih[(size_t)(n0 + r) * E_ + kk + kq];
            As[kq + 0][r] = av.x; As[kq + 1][r] = av.y;
            As[kq + 2][r] = av.z; As[kq + 3][r] = av.w;
            Bs[kq + 0][r] = bv.x; Bs[kq + 1][r] = bv.y;
            Bs[kq + 2][r] = bv.z; Bs[kq + 3][r] = bv.w;
        }
        __syncthreads();
#pragma unroll
        for (int k = 0; k < GKC; ++k) {
            float4 a0 = *(const float4*)&As[k][tm];
            float4 a1 = *(const float4*)&As[k][tm + 64];
            float4 b0 = *(const float4*)&Bs[k][tn];
            float4 b1 = *(const float4*)&Bs[k][tn + 64];
            float am[8] = {a0.x, a0.y, a0.z, a0.w, a1.x, a1.y, a1.z, a1.w};
            float bn[8] = {b0.x, b0.y, b0.z, b0.w, b1.x, b1.y, b1.z, b1.w};
#pragma unroll
            for (int i = 0; i < 8; ++i)
#pragma unroll
                for (int j = 0; j < 8; ++j)
                    acc[i][j] = fmaf(am[i], bn[j], acc[i][j]);
        }
    }
    float* out = Xg + ((size_t)dir * 8192 + m0) * 1024 + n0;
#pragma unroll
    for (int i = 0; i < 8; ++i) {
        int mr = (i < 4) ? (tm + i) : (tm + 60 + i);
        *(float4*)&out[(size_t)mr * 1024 + tn] =
            make_float4(acc[i][0], acc[i][1], acc[i][2], acc[i][3]);
        *(float4*)&out[(size_t)mr * 1024 + tn + 64] =
            make_float4(acc[i][4], acc[i][5], acc[i][6], acc[i][7]);
    }
}

// ---------------------------------------------------------------------------
// K2: LSTM, K-split pair, XCD-AWARE DYNAMIC PAIRING + dual-path exchange.
// 256 WGs x 512 thr (coop, co-resident). Each WG discovers its physical XCD
// via s_getreg(HW_REG_XCC_ID), registers in Reg[], grid-barriers, then ALL
// WGs deterministically pair consecutive same-XCD WGs into chains
// (chain P: dir=P&1, b=P>>1; members are side 0/1). Same-XCD pairs make the
// plain-store/sc0-load fast path an L2 round trip. Leftover cross-XCD pairs
// (and garbage XCC_ID) remain correct via the unconditional LLC atomic path.
// Per thread: rows r0=t, r1=t+512 over side's 128 cols:
//   39 pair-cols regs + 19 pair-cols LDS + 6 pair-cols streamed (sT).
// ---------------------------------------------------------------------------
#define RP_ 39
#define LP_ 19

__global__ __launch_bounds__(512, 2) void lstm_ks4_kernel(
    const float* __restrict__ Xg,     // [2][8192][1024]
    const float* __restrict__ Whh_f, const float* __restrict__ Whh_b,
    const float* __restrict__ b_f, const float* __restrict__ b_b,
    const int* __restrict__ lens,
    float* __restrict__ enc,          // [B][S][512]
    unsigned long long* __restrict__ Fch,  // [P=128][2 par][2 prodside][512]
    unsigned long long* __restrict__ Sch,  // [P=128][2 par][2 prodside][512]
    const float4* __restrict__ sT,    // [12][1024]
    int* __restrict__ Reg) {          // cnt[8] @0, bar @8, table[512] @16
    extern __shared__ f32x2 Wl[];     // [LP_][1024]
    __shared__ f32x2 h_sh2[64];       // own side's 128 h values
    __shared__ float g_sh[2][128];    // f,o handoff between consumer halves
    __shared__ int s_tab[8 + 512];    // cnt + table snapshot
    __shared__ int s_info[2];         // {chain P, side}
    const int w = blockIdx.x;
    const int t = threadIdx.x;

    // --- phase 0: register (wg -> xcd), grid barrier ---
    if (t == 0) {
        int xcd = __builtin_amdgcn_s_getreg(HWREG_XCC_ID) & 7;
        int slot = __hip_atomic_fetch_add(&Reg[xcd], 1, __ATOMIC_RELAXED,
                                          __HIP_MEMORY_SCOPE_AGENT) & 63;
        __hip_atomic_store(&Reg[16 + xcd * 64 + slot], w + 1, __ATOMIC_RELAXED,
                           __HIP_MEMORY_SCOPE_AGENT);
        __hip_atomic_fetch_add(&Reg[8], 1, __ATOMIC_RELEASE,
                               __HIP_MEMORY_SCOPE_AGENT);
        while (__hip_atomic_load(&Reg[8], __ATOMIC_ACQUIRE,
                                 __HIP_MEMORY_SCOPE_AGENT) < 256)
            __builtin_amdgcn_s_sleep(2);
    }
    __syncthreads();
    // --- phase 1: parallel table snapshot -> LDS ---
    if (t < 8)
        s_tab[t] = __hip_atomic_load(&Reg[t], __ATOMIC_RELAXED,
                                     __HIP_MEMORY_SCOPE_AGENT);
    if (t < 512)
        s_tab[8 + t] = __hip_atomic_load(&Reg[16 + t], __ATOMIC_RELAXED,
                                         __HIP_MEMORY_SCOPE_AGENT);
    __syncthreads();
    // --- phase 2: deterministic pairing (same scan on every WG) ---
    if (t == 0) {
        int chain = 0, side = 0, pc = 0;
        int lef[8];
        int nl = 0;
        for (int x = 0; x < 8; ++x) {
            int c = s_tab[x];
            if (c > 64) c = 64;
            for (int i = 0; i + 1 < c; i += 2) {
                int wa = s_tab[8 + x * 64 + i] - 1;
                int wb = s_tab[8 + x * 64 + i + 1] - 1;
                if (wa == w) { chain = pc; side = 0; }
                if (wb == w) { chain = pc; side = 1; }
                ++pc;
            }
            if (c & 1) lef[nl++] = s_tab[8 + x * 64 + c - 1] - 1;
        }
        for (int i = 0; i + 1 < nl; i += 2) {
            if (lef[i] == w)     { chain = pc; side = 0; }
            if (lef[i + 1] == w) { chain = pc; side = 1; }
            ++pc;
        }
        s_info[0] = chain;
        s_info[1] = side;
    }
    __syncthreads();
    const int P = s_info[0];
    const int side = s_info[1];
    const int dir = P & 1, b = P >> 1;

    const int r0 = t, r1 = t + 512;
    const int ul = t & 127;
    const int gc = t >> 8;            // 0: rows {i,g}, 1: rows {f,o}
    const bool mine = (((t >> 7) & 1) == side);  // wave-uniform
    const int base = side << 7;
    const int idx = (gc << 7) + ul;   // slot index 0..255
    const float* Whh = dir ? Whh_b : Whh_f;
    const int len = lens[b];

    // pin weights: rows r0, r1, cols [base, base+78) in regs
    f32x2 w0[RP_], w1[RP_];
    {
        const f32x2* p0 = (const f32x2*)(Whh + (size_t)r0 * H_ + base);
        const f32x2* p1 = (const f32x2*)(Whh + (size_t)r1 * H_ + base);
#pragma unroll
        for (int j = 0; j < RP_; ++j) { w0[j] = p0[j]; w1[j] = p1[j]; }
        // cols [base+78, base+116) in LDS
#pragma unroll
        for (int j = 0; j < LP_; ++j) {
            Wl[j * 1024 + r0] = p0[RP_ + j];
            Wl[j * 1024 + r1] = p1[RP_ + j];
        }
    }
    const float* bias = dir ? b_b : b_f;
    const float bias0 = bias[r0], bias1 = bias[r1];
    const float4* sT0 = sT + (size_t)(dir * 6 + side * 3) * 1024;

    // exchange pointers (per-parity precomputed)
    unsigned long long* fw0 = Fch + (((size_t)P * 2 + 0) * 2 + side) * 512 + 2 * idx;
    unsigned long long* fw1 = Fch + (((size_t)P * 2 + 1) * 2 + side) * 512 + 2 * idx;
    const unsigned long long* fr0 =
        Fch + (((size_t)P * 2 + 0) * 2 + (side ^ 1)) * 512 + 2 * idx;
    const unsigned long long* fr1 =
        Fch + (((size_t)P * 2 + 1) * 2 + (side ^ 1)) * 512 + 2 * idx;
    unsigned long long* sw0 = Sch + (((size_t)P * 2 + 0) * 2 + side) * 512 + 2 * idx;
    unsigned long long* sw1 = Sch + (((size_t)P * 2 + 1) * 2 + side) * 512 + 2 * idx;
    const unsigned long long* sr0 =
        Sch + (((size_t)P * 2 + 0) * 2 + (side ^ 1)) * 512 + 2 * idx;
    const unsigned long long* sr1 =
        Sch + (((size_t)P * 2 + 1) * 2 + (side ^ 1)) * 512 + 2 * idx;

    if (t < 64) h_sh2[t] = (f32x2){0.f, 0.f};
    float c = 0.f;                    // cell state (consumers with gc==0)
    __syncthreads();

    // x prefetch (consumers only)
    int srow = dir ? (len - 1) : 0;   // len >= 1 guaranteed
    float x0 = 0.f, x1 = 0.f;
    if (mine) {
        const float* xp = Xg + ((size_t)dir * 8192 + (size_t)srow * B_ + b) * 1024;
        x0 = xp[r0]; x1 = xp[r1];
    }

    for (int s = 0; s < S_; ++s) {
        // streamed weight pairs 58..63 (cols base+116..127), in flight
        float4 s00 = sT0[r0], s01 = sT0[1024 + r0], s02 = sT0[2048 + r0];
        float4 s10 = sT0[r1], s11 = sT0[1024 + r1], s12 = sT0[2048 + r1];
        // next-step x prefetch
        int srow_n = 0;
        float x0n = 0.f, x1n = 0.f;
        if (s + 1 < S_) {
            int ns = s + 1;
            srow_n = dir ? ((ns < len) ? (len - 1 - ns) : ns) : ns;
            if (mine) {
                const float* xp =
                    Xg + ((size_t)dir * 8192 + (size_t)srow_n * B_ + b) * 1024;
                x0n = xp[r0]; x1n = xp[r1];
            }
        }

        // partial dot over own side's 128 cols, rows r0 and r1
        f32x2 a0 = (f32x2){0.f, 0.f}, a1 = (f32x2){0.f, 0.f};
#pragma unroll
        for (int j = 0; j < RP_; ++j) {
            f32x2 hv = h_sh2[j];                  // broadcast
            a0 = __builtin_elementwise_fma(w0[j], hv, a0);
            a1 = __builtin_elementwise_fma(w1[j], hv, a1);
        }
#pragma unroll
        for (int j = 0; j < LP_; ++j) {
            f32x2 hv = h_sh2[RP_ + j];
            f32x2 wa = Wl[j * 1024 + r0];
            f32x2 wb = Wl[j * 1024 + r1];
            a0 = __builtin_elementwise_fma(wa, hv, a0);
            a1 = __builtin_elementwise_fma(wb, hv, a1);
        }
        {
            f32x2 h58 = h_sh2[58], h59 = h_sh2[59], h60 = h_sh2[60];
            f32x2 h61 = h_sh2[61], h62 = h_sh2[62], h63 = h_sh2[63];
            a0 = __builtin_elementwise_fma((f32x2){s00.x, s00.y}, h58, a0);
            a0 = __builtin_elementwise_fma((f32x2){s00.z, s00.w}, h59, a0);
            a0 = __builtin_elementwise_fma((f32x2){s01.x, s01.y}, h60, a0);
            a0 = __builtin_elementwise_fma((f32x2){s01.z, s01.w}, h61, a0);
            a0 = __builtin_elementwise_fma((f32x2){s02.x, s02.y}, h62, a0);
            a0 = __builtin_elementwise_fma((f32x2){s02.z, s02.w}, h63, a0);
            a1 = __builtin_elementwise_fma((f32x2){s10.x, s10.y}, h58, a1);
            a1 = __builtin_elementwise_fma((f32x2){s10.z, s10.w}, h59, a1);
            a1 = __builtin_elementwise_fma((f32x2){s11.x, s11.y}, h60, a1);
            a1 = __builtin_elementwise_fma((f32x2){s11.z, s11.w}, h61, a1);
            a1 = __builtin_elementwise_fma((f32x2){s12.x, s12.y}, h62, a1);
            a1 = __builtin_elementwise_fma((f32x2){s12.z, s12.w}, h63, a1);
        }
        float p0 = a0.x + a0.y, p1 = a1.x + a1.y;

        const unsigned tag = (unsigned)(s + 1);
        float iv = 0.f, gv = 0.f;
        if (!mine) {
            unsigned long long k0 =
                ((unsigned long long)tag << 32) | (unsigned long long)__float_as_uint(p0);
            unsigned long long k1 =
                ((unsigned long long)tag << 32) | (unsigned long long)__float_as_uint(p1);
            // fast path: two plain 8B stores, same 16B line (XCD L2)
            store_l2x2((s & 1) ? fw1 : fw0, k0, k1);
            // slow path: LLC-coherent packed atomics (placement-safe)
            unsigned long long* sb = (s & 1) ? sw1 : sw0;
            __hip_atomic_store(sb, k0, __ATOMIC_RELAXED, __HIP_MEMORY_SCOPE_AGENT);
            __hip_atomic_store(sb + 1, k1, __ATOMIC_RELAXED, __HIP_MEMORY_SCOPE_AGENT);
        } else {
            const unsigned long long* fr = (s & 1) ? fr1 : fr0;
            const unsigned long long* sr = (s & 1) ? sr1 : sr0;
            float q0f, q1f;
            for (;;) {
                unsigned long long f0, f1;
                load_l2x2(fr, f0, f1);
                if ((unsigned)(f0 >> 32) == tag && (unsigned)(f1 >> 32) == tag) {
                    q0f = __uint_as_float((unsigned)f0);
                    q1f = __uint_as_float((unsigned)f1);
                    break;
                }
                unsigned long long a0q = __hip_atomic_load(
                    sr, __ATOMIC_RELAXED, __HIP_MEMORY_SCOPE_AGENT);
                unsigned long long a1q = __hip_atomic_load(
                    sr + 1, __ATOMIC_RELAXED, __HIP_MEMORY_SCOPE_AGENT);
                if ((unsigned)(a0q >> 32) == tag && (unsigned)(a1q >> 32) == tag) {
                    q0f = __uint_as_float((unsigned)a0q);
                    q1f = __uint_as_float((unsigned)a1q);
                    break;
                }
            }
            float g0 = p0 + q0f + bias0 + x0;
            float g1 = p1 + q1f + bias1 + x1;
            if (gc == 0) {
                iv = sigmoid_acc(g0);            // i-gate (keep in regs)
                gv = tanh_acc(g1);               // g-gate
            } else {
                g_sh[0][ul] = sigmoid_acc(g0);   // f-gate
                g_sh[1][ul] = sigmoid_acc(g1);   // o-gate
            }
        }
        __syncthreads();   // SYNC1: g_sh ready; h_sh2 fully consumed

        if (mine && gc == 0) {
            float fv = g_sh[0][ul], ov = g_sh[1][ul];
            c = fv * c + iv * gv;
            float h = ov * tanh_acc(c);
            ((float*)h_sh2)[ul] = h;
            int orow = dir ? srow : s;
            enc[((size_t)b * S_ + orow) * 512 + dir * H_ + base + ul] =
                (orow < len) ? h : 0.f;
        }
        __syncthreads();   // SYNC2: h(s+1) ready for next step's dots

        srow = srow_n;
        x0 = x0n; x1 = x1n;
    }
}

// ---------------------------------------------------------------------------
// K3: U = enc@Ua^T, W = enc@Wa^T
// ---------------------------------------------------------------------------
__global__ __launch_bounds__(256) void uw_kernel(
    const float* __restrict__ enc, const float* __restrict__ Ua,
    const float* __restrict__ Wa, float* __restrict__ U, float* __restrict__ Wout) {
    __shared__ float wgt[60][129];
    __shared__ float erow[4][128];
    const int tid = threadIdx.x;
    const int b = blockIdx.y, s0 = blockIdx.x * 32;
    const int rl = tid >> 6;
    const int d = tid & 63;
    const int dd = d & 31;
    const int isW = d >> 5;
    float acc[8];
#pragma unroll
    for (int i = 0; i < 8; ++i) acc[i] = 0.f;

    for (int kk = 0; kk < 4; ++kk) {
        __syncthreads();
        for (int i = tid; i < 30 * 128; i += 256) {
            int r = i >> 7, k = i & 127;
            wgt[r][k] = Ua[(size_t)r * 512 + kk * 128 + k];
            wgt[r + 30][k] = Wa[(size_t)r * 512 + kk * 128 + k];
        }
        for (int chunk = 0; chunk < 8; ++chunk) {
            __syncthreads();
            for (int i = tid; i < 4 * 128; i += 256) {
                int r = i >> 7, k = i & 127;
                erow[r][k] = enc[((size_t)b * S_ + (s0 + chunk * 4 + r)) * 512 + kk * 128 + k];
            }
            __syncthreads();
            if (dd < HID_) {
                const float* wr = wgt[dd + 30 * isW];
                const float* er = erow[rl];
                float a = acc[chunk];
#pragma unroll
                for (int k = 0; k < 128; ++k) a = fmaf(er[k], wr[k], a);
                acc[chunk] = a;
            }
        }
    }
    if (dd < HID_) {
        float* dst = isW ? Wout : U;
#pragma unroll
        for (int chunk = 0; chunk < 8; ++chunk)
            dst[((size_t)b * S_ + (s0 + chunk * 4 + rl)) * 32 + dd] = acc[chunk];
    }
}

// ---------------------------------------------------------------------------
// K4: scores + predictions
// ---------------------------------------------------------------------------
__global__ __launch_bounds__(256) void scores_kernel(
    const float* __restrict__ U, const float* __restrict__ W,
    const float* __restrict__ va,
    float* __restrict__ scores, float* __restrict__ preds) {
    __shared__ float w_sh[128][31];
    const int b = blockIdx.y, i0 = blockIdx.x * 32;
    const int tid = threadIdx.x;

    float va_r[HID_];
#pragma unroll
    for (int d2 = 0; d2 < HID_; ++d2) va_r[d2] = va[d2];

    for (int i = tid; i < 128 * HID_; i += 256) {
        int r = i / HID_, d2 = i - r * HID_;
        w_sh[r][d2] = W[((size_t)b * S_ + r) * 32 + d2];
    }
    __syncthreads();

    const int il = tid >> 3;
    const int jb = (tid & 7) * 16;
    float u_r[HID_];
    const float* urow = U + ((size_t)b * S_ + i0 + il) * 32;
#pragma unroll
    for (int d2 = 0; d2 < HID_; ++d2) u_r[d2] = urow[d2];

    const size_t obase = ((size_t)b * S_ + (i0 + il)) * S_;
    for (int jj = 0; jj < 16; ++jj) {
        int j = jb + jj;
        float acc = 0.f;
#pragma unroll
        for (int d2 = 0; d2 < HID_; ++d2)
            acc = fmaf(va_r[d2], fast_tanh(u_r[d2] + w_sh[j][d2]), acc);
        scores[obase + j] = acc;
        preds[obase + j] = (sigmoid_acc(acc) >= 0.5f) ? 1.f : 0.f;
    }
}

// ---------------------------------------------------------------------------
// Workspace layout (bytes):
//   Xg   @ 0          : 2*8192*1024*4 = 67,108,864
//   enc  @ 67,108,864 : 64*128*512*4  = 16,777,216
//   U    @ 83,886,080 : 8192*32*4     =  1,048,576
//   W    @ 84,934,656 : 8192*32*4     =  1,048,576
//   Fch  @ 85,983,232 : 128*2*2*512*8 =  2,097,152
//   Sch  @ 88,080,384 : 128*2*2*512*8 =  2,097,152
//   sT   @ 90,177,536 : 12*1024*16    =    196,608
//   Reg  @ 90,374,144 : (16+512)*4    =      2,112 (pad 4096)
// ---------------------------------------------------------------------------
extern "C" void kernel_launch(void* const* d_in, const int* in_sizes, int n_in,
                              void* d_out, int out_size, void* d_ws, size_t ws_size,
                              hipStream_t stream) {
    (void)in_sizes; (void)n_in; (void)out_size; (void)ws_size;
    const int* concepts = (const int*)d_in[0];
    const int* lens = (const int*)d_in[1];
    const float* embedding = (const float*)d_in[2];
    const float* Wih_f = (const float*)d_in[3];
    const float* Whh_f = (const float*)d_in[4];
    const float* b_f = (const float*)d_in[5];
    const float* Wih_b = (const float*)d_in[6];
    const float* Whh_b = (const float*)d_in[7];
    const float* b_b = (const float*)d_in[8];
    const float* Ua = (const float*)d_in[9];
    const float* Wa = (const float*)d_in[10];
    const float* va = (const float*)d_in[11];

    char* ws = (char*)d_ws;
    float* Xg = (float*)(ws + 0);
    float* enc = (float*)(ws + 67108864);
    float* U = (float*)(ws + 83886080);
    float* W = (float*)(ws + 84934656);
    unsigned long long* Fch = (unsigned long long*)(ws + 85983232);
    unsigned long long* Sch = (unsigned long long*)(ws + 88080384);
    float4* sT = (float4*)(ws + 90177536);
    int* Reg = (int*)(ws + 90374144);

    float* scores = (float*)d_out;
    float* preds = scores + (size_t)B_ * S_ * S_;

    // zero handoff slots + registration table (tag/count 0 = empty)
    (void)hipMemsetAsync(Fch, 0, 2 * 2097152, stream);
    (void)hipMemsetAsync(Reg, 0, 4096, stream);

    hipLaunchKernelGGL(prep_stream_kernel, dim3(48), dim3(256), 0, stream,
                       Whh_f, Whh_b, sT);
    hipLaunchKernelGGL(gemm2_kernel, dim3(512, 2), dim3(256), 0, stream,
                       concepts, embedding, Wih_f, Wih_b, Xg);

    {
        const float* XgA = Xg;
        void* ka[] = {(void*)&XgA, (void*)&Whh_f, (void*)&Whh_b, (void*)&b_f,
                      (void*)&b_b, (void*)&lens, (void*)&enc, (void*)&Fch,
                      (void*)&Sch, (void*)&sT, (void*)&Reg};
        (void)hipLaunchCooperativeKernel((const void*)lstm_ks4_kernel, dim3(256),
                                         dim3(512), ka, LP_ * 1024 * sizeof(f32x2),
                                         stream);
    }

    hipLaunchKernelGGL(uw_kernel, dim3(4, 64), dim3(256), 0, stream,
                       enc, Ua, Wa, U, W);
    hipLaunchKernelGGL(scores_kernel, dim3(4, 64), dim3(256), 0, stream,
                       U, W, va, scores, preds);
}